// Round 6
// baseline (2440.426 us; speedup 1.0000x reference)
//
#include <hip/hip_runtime.h>
#include <hip/hip_bf16.h>
#include <math.h>

#define Bb 2
#define Nn 2048
#define Dd 512
#define Hh 16
#define DKk 32

// ---------------------------------------------------------------------------
// Kernel 1: fused QKV projection.
// X [4096 x 512] (q/k/v) times W [512 x 512] (proj per head, cols = h*32+dk)
// -> out [B,H,N,DK] (+bias).  Tile 128x64, K-step 32, 8x4 microtile/thread.
// ---------------------------------------------------------------------------
__global__ __launch_bounds__(256) void qkv_proj_kernel(
    const float* __restrict__ q, const float* __restrict__ k, const float* __restrict__ v,
    const float* __restrict__ q_proj, const float* __restrict__ k_proj, const float* __restrict__ v_proj,
    const float* __restrict__ q_bias, const float* __restrict__ k_bias, const float* __restrict__ v_bias,
    float* __restrict__ Qws, float* __restrict__ Kws, float* __restrict__ Vws)
{
    const int gz = blockIdx.z; // 0=q,1=k,2=v
    const float* __restrict__ X = (gz == 0) ? q : (gz == 1) ? k : v;
    const float* __restrict__ W = (gz == 0) ? q_proj : (gz == 1) ? k_proj : v_proj;
    const float* __restrict__ bias = (gz == 0) ? q_bias : (gz == 1) ? k_bias : v_bias;
    float* __restrict__ O = (gz == 0) ? Qws : (gz == 1) ? Kws : Vws;

    const int m0 = blockIdx.x * 128;
    const int c0 = blockIdx.y * 64;

    __shared__ float XsT[32][132];  // [kk][row], padded
    __shared__ float Ws[32][68];    // [kk][col], padded (16B-aligned rows)

    const int tid = threadIdx.x;
    const int tx = tid & 15;   // col group: cols 4*tx..4*tx+3
    const int ty = tid >> 4;   // row group: rows 8*ty..8*ty+7

    float acc[8][4];
    #pragma unroll
    for (int i = 0; i < 8; ++i)
        #pragma unroll
        for (int j = 0; j < 4; ++j) acc[i][j] = 0.f;

    for (int k0 = 0; k0 < 512; k0 += 32) {
        __syncthreads();
        // stage X tile (128 rows x 32 k) transposed into XsT
        #pragma unroll
        for (int it = 0; it < 4; ++it) {
            int u = tid + 256 * it;       // 0..1023
            int r = u >> 3, f = u & 7;
            float4 xv = *reinterpret_cast<const float4*>(&X[(size_t)(m0 + r) * 512 + k0 + 4 * f]);
            XsT[4 * f + 0][r] = xv.x;
            XsT[4 * f + 1][r] = xv.y;
            XsT[4 * f + 2][r] = xv.z;
            XsT[4 * f + 3][r] = xv.w;
        }
        // stage W tile (32 k x 64 cols)
        #pragma unroll
        for (int it = 0; it < 2; ++it) {
            int u = tid + 256 * it;       // 0..511
            int c4 = u & 15, kk = u >> 4;
            int c = c0 + 4 * c4;
            int h = c >> 5, dk = c & 31;
            float4 wv = *reinterpret_cast<const float4*>(&W[((size_t)h * 512 + k0 + kk) * 32 + dk]);
            *reinterpret_cast<float4*>(&Ws[kk][4 * c4]) = wv;
        }
        __syncthreads();
        #pragma unroll
        for (int kk = 0; kk < 32; ++kk) {
            float4 a0 = *reinterpret_cast<const float4*>(&XsT[kk][8 * ty]);
            float4 a1 = *reinterpret_cast<const float4*>(&XsT[kk][8 * ty + 4]);
            float4 bv = *reinterpret_cast<const float4*>(&Ws[kk][4 * tx]);
            float ar[8] = {a0.x, a0.y, a0.z, a0.w, a1.x, a1.y, a1.z, a1.w};
            float br[4] = {bv.x, bv.y, bv.z, bv.w};
            #pragma unroll
            for (int i = 0; i < 8; ++i)
                #pragma unroll
                for (int j = 0; j < 4; ++j) acc[i][j] = fmaf(ar[i], br[j], acc[i][j]);
        }
    }

    // epilogue: + bias, write to [B,H,N,DK]
    const int c = c0 + 4 * tx;
    const int h = c >> 5, dk = c & 31;
    float4 bq = *reinterpret_cast<const float4*>(&bias[h * 32 + dk]);
    #pragma unroll
    for (int i = 0; i < 8; ++i) {
        int m = m0 + 8 * ty + i;
        int bb = m >> 11, n = m & 2047;
        float4 ov;
        ov.x = acc[i][0] + bq.x;
        ov.y = acc[i][1] + bq.y;
        ov.z = acc[i][2] + bq.z;
        ov.w = acc[i][3] + bq.w;
        *reinterpret_cast<float4*>(&O[(((size_t)bb * 16 + h) * 2048 + n) * 32 + dk]) = ov;
    }
}

// ---------------------------------------------------------------------------
// Kernel 2: RBF-gated flash attention. 4-way j-split for occupancy:
// block = 256 threads = 64 query rows x 4 j-segments (one wave per segment,
// so K/V/coords reads stay wave-uniform). Grid 1024 blocks -> 16 waves/CU
// (4/SIMD, the VGPR-bin max at <=128 VGPR). Partials merged once via LDS.
// Mask in rbf-space vs 0.01/0.99 like the reference; __expf (v_exp_f32)
// replaces libm expf (input-rounding noise already dominates boundary flips;
// round-3 passed at absmax 0.0078 with the same d2 computation).
// Writes pre[b,n,dk*16+h] (the reference's (DK,H) interleave) for out-proj.
// ---------------------------------------------------------------------------
__global__ __launch_bounds__(256, 4) void attn_kernel(
    const float* __restrict__ Qws, const float* __restrict__ Kws, const float* __restrict__ Vws,
    const float* __restrict__ coords, const float* __restrict__ spreads,
    float* __restrict__ pre)
{
    const int b = blockIdx.z, h = blockIdx.y;
    const int tid = threadIdx.x;
    const int r = tid & 63;        // query row within block
    const int seg = tid >> 6;      // j-segment: seg*512 .. seg*512+511
    const int i = blockIdx.x * 64 + r;
    const int bh = b * 16 + h;

    const float sig = spreads[h];
    const float inv2s2 = 1.0f / (2.0f * sig * sig);
    const float scale = 0.17677669529663687f;   // 1/sqrt(32)

    const float* __restrict__ Cb = coords + (size_t)b * 2048 * 3;
    const float* __restrict__ Kb = Kws + (size_t)bh * 2048 * 32;
    const float* __restrict__ Vb = Vws + (size_t)bh * 2048 * 32;

    const float cix = Cb[(size_t)i * 3 + 0];
    const float ciy = Cb[(size_t)i * 3 + 1];
    const float ciz = Cb[(size_t)i * 3 + 2];

    float qf[32];
    #pragma unroll
    for (int u = 0; u < 8; ++u) {
        float4 t = *reinterpret_cast<const float4*>(&Qws[((size_t)bh * 2048 + i) * 32 + 4 * u]);
        qf[4 * u] = t.x; qf[4 * u + 1] = t.y; qf[4 * u + 2] = t.z; qf[4 * u + 3] = t.w;
    }

    float m = -INFINITY, l = 0.f;
    float o[32];
    #pragma unroll
    for (int kd = 0; kd < 32; ++kd) o[kd] = 0.f;

    const int jbeg = seg * 512;
    #pragma unroll 1
    for (int j0 = jbeg; j0 < jbeg + 512; j0 += 16) {
        float sv[16];
        float mt = -INFINITY;
        #pragma unroll
        for (int jj = 0; jj < 16; ++jj) {
            const int j = j0 + jj;
            // wave-uniform coord read
            const float cjx = Cb[(size_t)j * 3 + 0];
            const float cjy = Cb[(size_t)j * 3 + 1];
            const float cjz = Cb[(size_t)j * 3 + 2];
            const float dx = cix - cjx;
            const float dy = ciy - cjy;
            const float dz = ciz - cjz;
            const float d2 = fmaf(dx, dx, fmaf(dy, dy, dz * dz));

            // wave-uniform K row
            const float* __restrict__ kp = Kb + (size_t)j * 32;
            float p0 = 0.f, p1 = 0.f, p2 = 0.f, p3 = 0.f;
            #pragma unroll
            for (int u = 0; u < 8; ++u) {
                const float4 kv = *reinterpret_cast<const float4*>(kp + 4 * u);
                p0 = fmaf(qf[4 * u + 0], kv.x, p0);
                p1 = fmaf(qf[4 * u + 1], kv.y, p1);
                p2 = fmaf(qf[4 * u + 2], kv.z, p2);
                p3 = fmaf(qf[4 * u + 3], kv.w, p3);
            }
            const float qk = (p0 + p1) + (p2 + p3);
            const float rb = __expf(-d2 * inv2s2);
            const bool valid = (rb >= 0.01f) && (rb <= 0.99f);
            const float sc = valid ? qk * scale * (rb * rb) : -1e9f;
            sv[jj] = sc;
            mt = fmaxf(mt, sc);
        }

        const float mn = fmaxf(m, mt);
        const float em = __expf(m - mn);
        l *= em;
        #pragma unroll
        for (int kd = 0; kd < 32; ++kd) o[kd] *= em;

        #pragma unroll
        for (int jj = 0; jj < 16; ++jj) {
            const int j = j0 + jj;
            const float p = __expf(sv[jj] - mn);
            l += p;
            const float* __restrict__ vp = Vb + (size_t)j * 32;
            #pragma unroll
            for (int u = 0; u < 8; ++u) {
                const float4 vv = *reinterpret_cast<const float4*>(vp + 4 * u);
                o[4 * u + 0] = fmaf(p, vv.x, o[4 * u + 0]);
                o[4 * u + 1] = fmaf(p, vv.y, o[4 * u + 1]);
                o[4 * u + 2] = fmaf(p, vv.z, o[4 * u + 2]);
                o[4 * u + 3] = fmaf(p, vv.w, o[4 * u + 3]);
            }
        }
        m = mn;
    }

    // ---- merge the 4 j-segments via LDS (segs 1-3 publish, seg 0 merges) ----
    __shared__ float Lm[3][64];
    __shared__ float Ll[3][64];
    __shared__ float Lo[3][64][33];   // stride 33: bank (r*33+kd)%32 = (r+kd)%32, conflict-free
    if (seg != 0) {
        Lm[seg - 1][r] = m;
        Ll[seg - 1][r] = l;
        #pragma unroll
        for (int kd = 0; kd < 32; ++kd) Lo[seg - 1][r][kd] = o[kd];
    }
    __syncthreads();
    if (seg == 0) {
        float mn = m;
        #pragma unroll
        for (int s = 0; s < 3; ++s) mn = fmaxf(mn, Lm[s][r]);
        const float e0 = __expf(m - mn);
        float lt = l * e0;
        float es[3];
        #pragma unroll
        for (int s = 0; s < 3; ++s) {
            es[s] = __expf(Lm[s][r] - mn);
            lt = fmaf(Ll[s][r], es[s], lt);
        }
        const float invl = 1.0f / lt;
        const size_t base = ((size_t)b * 2048 + i) * 512 + h;
        #pragma unroll
        for (int kd = 0; kd < 32; ++kd) {
            float acc = o[kd] * e0;
            #pragma unroll
            for (int s = 0; s < 3; ++s) acc = fmaf(Lo[s][r][kd], es[s], acc);
            pre[base + (size_t)kd * 16] = acc * invl;
        }
    }
}

// ---------------------------------------------------------------------------
// Kernel 3: out = pre @ w_out^T.  Same GEMM structure as kernel 1;
// w_out staged transposed in LDS.
// ---------------------------------------------------------------------------
__global__ __launch_bounds__(256) void out_proj_kernel(
    const float* __restrict__ pre, const float* __restrict__ w_out,
    float* __restrict__ out)
{
    const int m0 = blockIdx.x * 128;
    const int d0 = blockIdx.y * 64;

    __shared__ float XsT[32][132];  // [ck][row]
    __shared__ float Bs[32][68];    // [ck][dcol]

    const int tid = threadIdx.x;
    const int tx = tid & 15;
    const int ty = tid >> 4;

    float acc[8][4];
    #pragma unroll
    for (int i = 0; i < 8; ++i)
        #pragma unroll
        for (int j = 0; j < 4; ++j) acc[i][j] = 0.f;

    for (int k0 = 0; k0 < 512; k0 += 32) {
        __syncthreads();
        #pragma unroll
        for (int it = 0; it < 4; ++it) {
            int u = tid + 256 * it;
            int r = u >> 3, f = u & 7;
            float4 xv = *reinterpret_cast<const float4*>(&pre[(size_t)(m0 + r) * 512 + k0 + 4 * f]);
            XsT[4 * f + 0][r] = xv.x;
            XsT[4 * f + 1][r] = xv.y;
            XsT[4 * f + 2][r] = xv.z;
            XsT[4 * f + 3][r] = xv.w;
        }
        #pragma unroll
        for (int it = 0; it < 2; ++it) {
            int u = tid + 256 * it;   // 0..511
            int dd = u >> 3, cf = u & 7;
            float4 wv = *reinterpret_cast<const float4*>(&w_out[(size_t)(d0 + dd) * 512 + k0 + 4 * cf]);
            Bs[4 * cf + 0][dd] = wv.x;
            Bs[4 * cf + 1][dd] = wv.y;
            Bs[4 * cf + 2][dd] = wv.z;
            Bs[4 * cf + 3][dd] = wv.w;
        }
        __syncthreads();
        #pragma unroll
        for (int kk = 0; kk < 32; ++kk) {
            float4 a0 = *reinterpret_cast<const float4*>(&XsT[kk][8 * ty]);
            float4 a1 = *reinterpret_cast<const float4*>(&XsT[kk][8 * ty + 4]);
            float4 bv = *reinterpret_cast<const float4*>(&Bs[kk][4 * tx]);
            float ar[8] = {a0.x, a0.y, a0.z, a0.w, a1.x, a1.y, a1.z, a1.w};
            float br[4] = {bv.x, bv.y, bv.z, bv.w};
            #pragma unroll
            for (int i = 0; i < 8; ++i)
                #pragma unroll
                for (int j = 0; j < 4; ++j) acc[i][j] = fmaf(ar[i], br[j], acc[i][j]);
        }
    }

    #pragma unroll
    for (int i = 0; i < 8; ++i) {
        int m = m0 + 8 * ty + i;
        float4 ov;
        ov.x = acc[i][0];
        ov.y = acc[i][1];
        ov.z = acc[i][2];
        ov.w = acc[i][3];
        *reinterpret_cast<float4*>(&out[(size_t)m * 512 + d0 + 4 * tx]) = ov;
    }
}

// ---------------------------------------------------------------------------
extern "C" void kernel_launch(void* const* d_in, const int* in_sizes, int n_in,
                              void* d_out, int out_size, void* d_ws, size_t ws_size,
                              hipStream_t stream) {
    const float* q       = (const float*)d_in[0];
    const float* k       = (const float*)d_in[1];
    const float* v       = (const float*)d_in[2];
    const float* coords  = (const float*)d_in[3];
    const float* q_proj  = (const float*)d_in[4];
    const float* k_proj  = (const float*)d_in[5];
    const float* v_proj  = (const float*)d_in[6];
    const float* q_bias  = (const float*)d_in[7];
    const float* k_bias  = (const float*)d_in[8];
    const float* v_bias  = (const float*)d_in[9];
    const float* w_out   = (const float*)d_in[10];
    const float* spreads = (const float*)d_in[11];
    float* out = (float*)d_out;

    // workspace layout (floats): Q | K | V | pre   (each B*H*N*DK = 2M, pre = B*N*D = 2M)
    float* Qws = (float*)d_ws;
    float* Kws = Qws + (size_t)Bb * Hh * Nn * DKk;
    float* Vws = Kws + (size_t)Bb * Hh * Nn * DKk;
    float* pre = Vws + (size_t)Bb * Hh * Nn * DKk;

    {
        dim3 grid(4096 / 128, 512 / 64, 3);
        qkv_proj_kernel<<<grid, 256, 0, stream>>>(q, k, v, q_proj, k_proj, v_proj,
                                                  q_bias, k_bias, v_bias, Qws, Kws, Vws);
    }
    {
        dim3 grid(Nn / 64, Hh, Bb);  // 4-way j-split: 64 rows/block, 1024 blocks
        attn_kernel<<<grid, 256, 0, stream>>>(Qws, Kws, Vws, coords, spreads, pre);
    }
    {
        dim3 grid(4096 / 128, 512 / 64);
        out_proj_kernel<<<grid, 256, 0, stream>>>(pre, w_out, out);
    }
}

// Round 8
// 1315.067 us; speedup vs baseline: 1.8557x; 1.8557x over previous
//
#include <hip/hip_runtime.h>
#include <hip/hip_bf16.h>
#include <math.h>

#define Bb 2
#define Nn 2048
#define Dd 512
#define Hh 16
#define DKk 32

// ---------------------------------------------------------------------------
// Kernel 1: fused QKV projection.
// X [4096 x 512] (q/k/v) times W [512 x 512] (proj per head, cols = h*32+dk)
// -> out [B,H,N,DK] (+bias).  Tile 128x64, K-step 32, 8x4 microtile/thread.
// ---------------------------------------------------------------------------
__global__ __launch_bounds__(256) void qkv_proj_kernel(
    const float* __restrict__ q, const float* __restrict__ k, const float* __restrict__ v,
    const float* __restrict__ q_proj, const float* __restrict__ k_proj, const float* __restrict__ v_proj,
    const float* __restrict__ q_bias, const float* __restrict__ k_bias, const float* __restrict__ v_bias,
    float* __restrict__ Qws, float* __restrict__ Kws, float* __restrict__ Vws)
{
    const int gz = blockIdx.z; // 0=q,1=k,2=v
    const float* __restrict__ X = (gz == 0) ? q : (gz == 1) ? k : v;
    const float* __restrict__ W = (gz == 0) ? q_proj : (gz == 1) ? k_proj : v_proj;
    const float* __restrict__ bias = (gz == 0) ? q_bias : (gz == 1) ? k_bias : v_bias;
    float* __restrict__ O = (gz == 0) ? Qws : (gz == 1) ? Kws : Vws;

    const int m0 = blockIdx.x * 128;
    const int c0 = blockIdx.y * 64;

    __shared__ float XsT[32][132];  // [kk][row], padded
    __shared__ float Ws[32][68];    // [kk][col], padded (16B-aligned rows)

    const int tid = threadIdx.x;
    const int tx = tid & 15;   // col group: cols 4*tx..4*tx+3
    const int ty = tid >> 4;   // row group: rows 8*ty..8*ty+7

    float acc[8][4];
    #pragma unroll
    for (int i = 0; i < 8; ++i)
        #pragma unroll
        for (int j = 0; j < 4; ++j) acc[i][j] = 0.f;

    for (int k0 = 0; k0 < 512; k0 += 32) {
        __syncthreads();
        // stage X tile (128 rows x 32 k) transposed into XsT
        #pragma unroll
        for (int it = 0; it < 4; ++it) {
            int u = tid + 256 * it;       // 0..1023
            int r = u >> 3, f = u & 7;
            float4 xv = *reinterpret_cast<const float4*>(&X[(size_t)(m0 + r) * 512 + k0 + 4 * f]);
            XsT[4 * f + 0][r] = xv.x;
            XsT[4 * f + 1][r] = xv.y;
            XsT[4 * f + 2][r] = xv.z;
            XsT[4 * f + 3][r] = xv.w;
        }
        // stage W tile (32 k x 64 cols)
        #pragma unroll
        for (int it = 0; it < 2; ++it) {
            int u = tid + 256 * it;       // 0..511
            int c4 = u & 15, kk = u >> 4;
            int c = c0 + 4 * c4;
            int h = c >> 5, dk = c & 31;
            float4 wv = *reinterpret_cast<const float4*>(&W[((size_t)h * 512 + k0 + kk) * 32 + dk]);
            *reinterpret_cast<float4*>(&Ws[kk][4 * c4]) = wv;
        }
        __syncthreads();
        #pragma unroll
        for (int kk = 0; kk < 32; ++kk) {
            float4 a0 = *reinterpret_cast<const float4*>(&XsT[kk][8 * ty]);
            float4 a1 = *reinterpret_cast<const float4*>(&XsT[kk][8 * ty + 4]);
            float4 bv = *reinterpret_cast<const float4*>(&Ws[kk][4 * tx]);
            float ar[8] = {a0.x, a0.y, a0.z, a0.w, a1.x, a1.y, a1.z, a1.w};
            float br[4] = {bv.x, bv.y, bv.z, bv.w};
            #pragma unroll
            for (int i = 0; i < 8; ++i)
                #pragma unroll
                for (int j = 0; j < 4; ++j) acc[i][j] = fmaf(ar[i], br[j], acc[i][j]);
        }
    }

    // epilogue: + bias, write to [B,H,N,DK]
    const int c = c0 + 4 * tx;
    const int h = c >> 5, dk = c & 31;
    float4 bq = *reinterpret_cast<const float4*>(&bias[h * 32 + dk]);
    #pragma unroll
    for (int i = 0; i < 8; ++i) {
        int m = m0 + 8 * ty + i;
        int bb = m >> 11, n = m & 2047;
        float4 ov;
        ov.x = acc[i][0] + bq.x;
        ov.y = acc[i][1] + bq.y;
        ov.z = acc[i][2] + bq.z;
        ov.w = acc[i][3] + bq.w;
        *reinterpret_cast<float4*>(&O[(((size_t)bb * 16 + h) * 2048 + n) * 32 + dk]) = ov;
    }
}

// ---------------------------------------------------------------------------
// Kernel 2: RBF-gated flash attention. 4-way j-split for occupancy:
// block = 256 threads = 64 query rows x 4 j-segments (one wave per segment,
// so K/V/coords reads stay wave-uniform). Grid 1024 blocks -> 16 waves/CU.
// NOTE: no min-waves launch_bounds hint — (256,4) capped the allocator at
// 64 VGPR (unified-file semantics) and spilled ~half the thread state:
// 6.5 GB scratch traffic/dispatch, 2x slowdown (round-6 counters). Natural
// allocation is ~112 VGPR (round 3), inside the <=128 bin -> 4 waves/SIMD.
// Partials merged once via LDS. Mask in rbf-space vs 0.01/0.99 like the
// reference; __expf for all exps (round-3 passed at absmax 0.0078).
// Writes pre[b,n,dk*16+h] (the reference's (DK,H) interleave) for out-proj.
// ---------------------------------------------------------------------------
__global__ __launch_bounds__(256) void attn_kernel(
    const float* __restrict__ Qws, const float* __restrict__ Kws, const float* __restrict__ Vws,
    const float* __restrict__ coords, const float* __restrict__ spreads,
    float* __restrict__ pre)
{
    const int b = blockIdx.z, h = blockIdx.y;
    const int tid = threadIdx.x;
    const int r = tid & 63;        // query row within block
    const int seg = tid >> 6;      // j-segment: seg*512 .. seg*512+511
    const int i = blockIdx.x * 64 + r;
    const int bh = b * 16 + h;

    const float sig = spreads[h];
    const float inv2s2 = 1.0f / (2.0f * sig * sig);
    const float scale = 0.17677669529663687f;   // 1/sqrt(32)

    const float* __restrict__ Cb = coords + (size_t)b * 2048 * 3;
    const float* __restrict__ Kb = Kws + (size_t)bh * 2048 * 32;
    const float* __restrict__ Vb = Vws + (size_t)bh * 2048 * 32;

    const float cix = Cb[(size_t)i * 3 + 0];
    const float ciy = Cb[(size_t)i * 3 + 1];
    const float ciz = Cb[(size_t)i * 3 + 2];

    float qf[32];
    #pragma unroll
    for (int u = 0; u < 8; ++u) {
        float4 t = *reinterpret_cast<const float4*>(&Qws[((size_t)bh * 2048 + i) * 32 + 4 * u]);
        qf[4 * u] = t.x; qf[4 * u + 1] = t.y; qf[4 * u + 2] = t.z; qf[4 * u + 3] = t.w;
    }

    float m = -INFINITY, l = 0.f;
    float o[32];
    #pragma unroll
    for (int kd = 0; kd < 32; ++kd) o[kd] = 0.f;

    const int jbeg = seg * 512;
    #pragma unroll 1
    for (int j0 = jbeg; j0 < jbeg + 512; j0 += 16) {
        float sv[16];
        float mt = -INFINITY;
        #pragma unroll
        for (int jj = 0; jj < 16; ++jj) {
            const int j = j0 + jj;
            // wave-uniform coord read
            const float cjx = Cb[(size_t)j * 3 + 0];
            const float cjy = Cb[(size_t)j * 3 + 1];
            const float cjz = Cb[(size_t)j * 3 + 2];
            const float dx = cix - cjx;
            const float dy = ciy - cjy;
            const float dz = ciz - cjz;
            const float d2 = fmaf(dx, dx, fmaf(dy, dy, dz * dz));

            // wave-uniform K row
            const float* __restrict__ kp = Kb + (size_t)j * 32;
            float p0 = 0.f, p1 = 0.f, p2 = 0.f, p3 = 0.f;
            #pragma unroll
            for (int u = 0; u < 8; ++u) {
                const float4 kv = *reinterpret_cast<const float4*>(kp + 4 * u);
                p0 = fmaf(qf[4 * u + 0], kv.x, p0);
                p1 = fmaf(qf[4 * u + 1], kv.y, p1);
                p2 = fmaf(qf[4 * u + 2], kv.z, p2);
                p3 = fmaf(qf[4 * u + 3], kv.w, p3);
            }
            const float qk = (p0 + p1) + (p2 + p3);
            const float rb = __expf(-d2 * inv2s2);
            const bool valid = (rb >= 0.01f) && (rb <= 0.99f);
            const float sc = valid ? qk * scale * (rb * rb) : -1e9f;
            sv[jj] = sc;
            mt = fmaxf(mt, sc);
        }

        const float mn = fmaxf(m, mt);
        const float em = __expf(m - mn);
        l *= em;
        #pragma unroll
        for (int kd = 0; kd < 32; ++kd) o[kd] *= em;

        #pragma unroll
        for (int jj = 0; jj < 16; ++jj) {
            const int j = j0 + jj;
            const float p = __expf(sv[jj] - mn);
            l += p;
            const float* __restrict__ vp = Vb + (size_t)j * 32;
            #pragma unroll
            for (int u = 0; u < 8; ++u) {
                const float4 vv = *reinterpret_cast<const float4*>(vp + 4 * u);
                o[4 * u + 0] = fmaf(p, vv.x, o[4 * u + 0]);
                o[4 * u + 1] = fmaf(p, vv.y, o[4 * u + 1]);
                o[4 * u + 2] = fmaf(p, vv.z, o[4 * u + 2]);
                o[4 * u + 3] = fmaf(p, vv.w, o[4 * u + 3]);
            }
        }
        m = mn;
    }

    // ---- merge the 4 j-segments via LDS (segs 1-3 publish, seg 0 merges) ----
    __shared__ float Lm[3][64];
    __shared__ float Ll[3][64];
    __shared__ float Lo[3][64][33];   // stride 33: bank (r*33+kd)%32 = (r+kd)%32, conflict-free
    if (seg != 0) {
        Lm[seg - 1][r] = m;
        Ll[seg - 1][r] = l;
        #pragma unroll
        for (int kd = 0; kd < 32; ++kd) Lo[seg - 1][r][kd] = o[kd];
    }
    __syncthreads();
    if (seg == 0) {
        float mn = m;
        #pragma unroll
        for (int s = 0; s < 3; ++s) mn = fmaxf(mn, Lm[s][r]);
        const float e0 = __expf(m - mn);
        float lt = l * e0;
        float es[3];
        #pragma unroll
        for (int s = 0; s < 3; ++s) {
            es[s] = __expf(Lm[s][r] - mn);
            lt = fmaf(Ll[s][r], es[s], lt);
        }
        const float invl = 1.0f / lt;
        const size_t base = ((size_t)b * 2048 + i) * 512 + h;
        #pragma unroll
        for (int kd = 0; kd < 32; ++kd) {
            float acc = o[kd] * e0;
            #pragma unroll
            for (int s = 0; s < 3; ++s) acc = fmaf(Lo[s][r][kd], es[s], acc);
            pre[base + (size_t)kd * 16] = acc * invl;
        }
    }
}

// ---------------------------------------------------------------------------
// Kernel 3: out = pre @ w_out^T.  Same GEMM structure as kernel 1;
// w_out staged transposed in LDS.
// ---------------------------------------------------------------------------
__global__ __launch_bounds__(256) void out_proj_kernel(
    const float* __restrict__ pre, const float* __restrict__ w_out,
    float* __restrict__ out)
{
    const int m0 = blockIdx.x * 128;
    const int d0 = blockIdx.y * 64;

    __shared__ float XsT[32][132];  // [ck][row]
    __shared__ float Bs[32][68];    // [ck][dcol]

    const int tid = threadIdx.x;
    const int tx = tid & 15;
    const int ty = tid >> 4;

    float acc[8][4];
    #pragma unroll
    for (int i = 0; i < 8; ++i)
        #pragma unroll
        for (int j = 0; j < 4; ++j) acc[i][j] = 0.f;

    for (int k0 = 0; k0 < 512; k0 += 32) {
        __syncthreads();
        #pragma unroll
        for (int it = 0; it < 4; ++it) {
            int u = tid + 256 * it;
            int r = u >> 3, f = u & 7;
            float4 xv = *reinterpret_cast<const float4*>(&pre[(size_t)(m0 + r) * 512 + k0 + 4 * f]);
            XsT[4 * f + 0][r] = xv.x;
            XsT[4 * f + 1][r] = xv.y;
            XsT[4 * f + 2][r] = xv.z;
            XsT[4 * f + 3][r] = xv.w;
        }
        #pragma unroll
        for (int it = 0; it < 2; ++it) {
            int u = tid + 256 * it;   // 0..511
            int dd = u >> 3, cf = u & 7;
            float4 wv = *reinterpret_cast<const float4*>(&w_out[(size_t)(d0 + dd) * 512 + k0 + 4 * cf]);
            Bs[4 * cf + 0][dd] = wv.x;
            Bs[4 * cf + 1][dd] = wv.y;
            Bs[4 * cf + 2][dd] = wv.z;
            Bs[4 * cf + 3][dd] = wv.w;
        }
        __syncthreads();
        #pragma unroll
        for (int kk = 0; kk < 32; ++kk) {
            float4 a0 = *reinterpret_cast<const float4*>(&XsT[kk][8 * ty]);
            float4 a1 = *reinterpret_cast<const float4*>(&XsT[kk][8 * ty + 4]);
            float4 bv = *reinterpret_cast<const float4*>(&Bs[kk][4 * tx]);
            float ar[8] = {a0.x, a0.y, a0.z, a0.w, a1.x, a1.y, a1.z, a1.w};
            float br[4] = {bv.x, bv.y, bv.z, bv.w};
            #pragma unroll
            for (int i = 0; i < 8; ++i)
                #pragma unroll
                for (int j = 0; j < 4; ++j) acc[i][j] = fmaf(ar[i], br[j], acc[i][j]);
        }
    }

    #pragma unroll
    for (int i = 0; i < 8; ++i) {
        int m = m0 + 8 * ty + i;
        float4 ov;
        ov.x = acc[i][0];
        ov.y = acc[i][1];
        ov.z = acc[i][2];
        ov.w = acc[i][3];
        *reinterpret_cast<float4*>(&out[(size_t)m * 512 + d0 + 4 * tx]) = ov;
    }
}

// ---------------------------------------------------------------------------
extern "C" void kernel_launch(void* const* d_in, const int* in_sizes, int n_in,
                              void* d_out, int out_size, void* d_ws, size_t ws_size,
                              hipStream_t stream) {
    const float* q       = (const float*)d_in[0];
    const float* k       = (const float*)d_in[1];
    const float* v       = (const float*)d_in[2];
    const float* coords  = (const float*)d_in[3];
    const float* q_proj  = (const float*)d_in[4];
    const float* k_proj  = (const float*)d_in[5];
    const float* v_proj  = (const float*)d_in[6];
    const float* q_bias  = (const float*)d_in[7];
    const float* k_bias  = (const float*)d_in[8];
    const float* v_bias  = (const float*)d_in[9];
    const float* w_out   = (const float*)d_in[10];
    const float* spreads = (const float*)d_in[11];
    float* out = (float*)d_out;

    // workspace layout (floats): Q | K | V | pre   (each B*H*N*DK = 2M, pre = B*N*D = 2M)
    float* Qws = (float*)d_ws;
    float* Kws = Qws + (size_t)Bb * Hh * Nn * DKk;
    float* Vws = Kws + (size_t)Bb * Hh * Nn * DKk;
    float* pre = Vws + (size_t)Bb * Hh * Nn * DKk;

    {
        dim3 grid(4096 / 128, 512 / 64, 3);
        qkv_proj_kernel<<<grid, 256, 0, stream>>>(q, k, v, q_proj, k_proj, v_proj,
                                                  q_bias, k_bias, v_bias, Qws, Kws, Vws);
    }
    {
        dim3 grid(Nn / 64, Hh, Bb);  // 4-way j-split: 64 rows/block, 1024 blocks
        attn_kernel<<<grid, 256, 0, stream>>>(Qws, Kws, Vws, coords, spreads, pre);
    }
    {
        dim3 grid(4096 / 128, 512 / 64);
        out_proj_kernel<<<grid, 256, 0, stream>>>(pre, w_out, out);
    }
}

// Round 10
// 670.107 us; speedup vs baseline: 3.6418x; 1.9625x over previous
//
#include <hip/hip_runtime.h>
#include <hip/hip_bf16.h>
#include <math.h>

#define Bb 2
#define Nn 2048
#define Dd 512
#define Hh 16
#define DKk 32

// ---------------------------------------------------------------------------
// Kernel 1: fused QKV projection (unchanged).
// ---------------------------------------------------------------------------
__global__ __launch_bounds__(256) void qkv_proj_kernel(
    const float* __restrict__ q, const float* __restrict__ k, const float* __restrict__ v,
    const float* __restrict__ q_proj, const float* __restrict__ k_proj, const float* __restrict__ v_proj,
    const float* __restrict__ q_bias, const float* __restrict__ k_bias, const float* __restrict__ v_bias,
    float* __restrict__ Qws, float* __restrict__ Kws, float* __restrict__ Vws)
{
    const int gz = blockIdx.z; // 0=q,1=k,2=v
    const float* __restrict__ X = (gz == 0) ? q : (gz == 1) ? k : v;
    const float* __restrict__ W = (gz == 0) ? q_proj : (gz == 1) ? k_proj : v_proj;
    const float* __restrict__ bias = (gz == 0) ? q_bias : (gz == 1) ? k_bias : v_bias;
    float* __restrict__ O = (gz == 0) ? Qws : (gz == 1) ? Kws : Vws;

    const int m0 = blockIdx.x * 128;
    const int c0 = blockIdx.y * 64;

    __shared__ float XsT[32][132];
    __shared__ float Ws[32][68];

    const int tid = threadIdx.x;
    const int tx = tid & 15;
    const int ty = tid >> 4;

    float acc[8][4];
    #pragma unroll
    for (int i = 0; i < 8; ++i)
        #pragma unroll
        for (int j = 0; j < 4; ++j) acc[i][j] = 0.f;

    for (int k0 = 0; k0 < 512; k0 += 32) {
        __syncthreads();
        #pragma unroll
        for (int it = 0; it < 4; ++it) {
            int u = tid + 256 * it;
            int r = u >> 3, f = u & 7;
            float4 xv = *reinterpret_cast<const float4*>(&X[(size_t)(m0 + r) * 512 + k0 + 4 * f]);
            XsT[4 * f + 0][r] = xv.x;
            XsT[4 * f + 1][r] = xv.y;
            XsT[4 * f + 2][r] = xv.z;
            XsT[4 * f + 3][r] = xv.w;
        }
        #pragma unroll
        for (int it = 0; it < 2; ++it) {
            int u = tid + 256 * it;
            int c4 = u & 15, kk = u >> 4;
            int c = c0 + 4 * c4;
            int h = c >> 5, dk = c & 31;
            float4 wv = *reinterpret_cast<const float4*>(&W[((size_t)h * 512 + k0 + kk) * 32 + dk]);
            *reinterpret_cast<float4*>(&Ws[kk][4 * c4]) = wv;
        }
        __syncthreads();
        #pragma unroll
        for (int kk = 0; kk < 32; ++kk) {
            float4 a0 = *reinterpret_cast<const float4*>(&XsT[kk][8 * ty]);
            float4 a1 = *reinterpret_cast<const float4*>(&XsT[kk][8 * ty + 4]);
            float4 bv = *reinterpret_cast<const float4*>(&Ws[kk][4 * tx]);
            float ar[8] = {a0.x, a0.y, a0.z, a0.w, a1.x, a1.y, a1.z, a1.w};
            float br[4] = {bv.x, bv.y, bv.z, bv.w};
            #pragma unroll
            for (int i = 0; i < 8; ++i)
                #pragma unroll
                for (int j = 0; j < 4; ++j) acc[i][j] = fmaf(ar[i], br[j], acc[i][j]);
        }
    }

    const int c = c0 + 4 * tx;
    const int h = c >> 5, dk = c & 31;
    float4 bq = *reinterpret_cast<const float4*>(&bias[h * 32 + dk]);
    #pragma unroll
    for (int i = 0; i < 8; ++i) {
        int m = m0 + 8 * ty + i;
        int bb = m >> 11, n = m & 2047;
        float4 ov;
        ov.x = acc[i][0] + bq.x;
        ov.y = acc[i][1] + bq.y;
        ov.z = acc[i][2] + bq.z;
        ov.w = acc[i][3] + bq.w;
        *reinterpret_cast<float4*>(&O[(((size_t)bb * 16 + h) * 2048 + n) * 32 + dk]) = ov;
    }
}

// ---------------------------------------------------------------------------
// Kernel 2: RBF-gated flash attention, LDS-staged double-buffered K/V tiles.
//
// Round-8 evidence: uniform K/V loads scalarize to s_load (SGPR=112) but the
// SGPR file can't hold a chunk's 2KB of K -> inner loop serializes on ~200cy
// scalar-cache latency (VALUBusy 27%, occupancy capped at 2 waves/SIMD by the
// (64,128] VGPR bin regardless of grid). Fix latency per wave, not waves:
//   - block = 256 thr = 4 waves share one 64-j tile (K,V,coords) in LDS,
//     double-buffered; wave seg computes the 16-j quarter [seg*16, seg*16+16)
//     of each tile (j-partition changes; online-softmax + merge unchanged).
//   - prefetch tile t+1 via __builtin_amdgcn_global_load_lds (width 16,
//     linear LDS dest = wave-uniform base + lane*16, coalesced global src)
//     issued BEFORE computing tile t -> HBM/L2 latency hides under compute.
//   - inner-loop reads are same-address broadcast ds_read_b128: conflict-free,
//     ~64cy deterministic, no SGPR pressure.
// LDS 60.3KB -> 2 blocks/CU, matching the VGPR occupancy cap (no loss).
// ---------------------------------------------------------------------------
__global__ __launch_bounds__(256) void attn_kernel(
    const float* __restrict__ Qws, const float* __restrict__ Kws, const float* __restrict__ Vws,
    const float* __restrict__ coords, const float* __restrict__ spreads,
    float* __restrict__ pre)
{
    const int b = blockIdx.z, h = blockIdx.y;
    const int tid = threadIdx.x;
    const int r = tid & 63;        // query row within block (lane)
    const int seg = tid >> 6;      // wave id = j-quarter within each tile
    const int i = blockIdx.x * 64 + r;
    const int bh = b * 16 + h;

    const float sig = spreads[h];
    const float inv2s2 = 1.0f / (2.0f * sig * sig);
    const float scale = 0.17677669529663687f;   // 1/sqrt(32)

    const float* __restrict__ Cb = coords + (size_t)b * 2048 * 3;
    const float* __restrict__ Kb = Kws + (size_t)bh * 2048 * 32;
    const float* __restrict__ Vb = Vws + (size_t)bh * 2048 * 32;

    const float cix = Cb[(size_t)i * 3 + 0];
    const float ciy = Cb[(size_t)i * 3 + 1];
    const float ciz = Cb[(size_t)i * 3 + 2];

    float qf[32];
    #pragma unroll
    for (int u = 0; u < 8; ++u) {
        float4 t = *reinterpret_cast<const float4*>(&Qws[((size_t)bh * 2048 + i) * 32 + 4 * u]);
        qf[4 * u] = t.x; qf[4 * u + 1] = t.y; qf[4 * u + 2] = t.z; qf[4 * u + 3] = t.w;
    }

    // double-buffered tiles: K,V 64x32 f32 each; coords 64x float4
    __shared__ float Kt[2][64 * 32];   // 16 KB
    __shared__ float Vt[2][64 * 32];   // 16 KB
    __shared__ float4 Ct[2][64];       // 2 KB

    // stage tile t (j0 = t*64) into buffer nb: 512 16B-chunks each for K and V,
    // chunk c -> row c>>3, float4-col c&7; threads cover c = tid, tid+256.
    #define STAGE(nb, t)                                                                  \
    {                                                                                     \
        const int j0_ = (t) * 64;                                                         \
        _Pragma("unroll")                                                                 \
        for (int it_ = 0; it_ < 2; ++it_) {                                               \
            const int c_ = tid + it_ * 256;                                               \
            const int jr_ = c_ >> 3, f4_ = c_ & 7;                                        \
            __builtin_amdgcn_global_load_lds(                                             \
                (const __attribute__((address_space(1))) void*)(const void*)              \
                    (Kb + (size_t)(j0_ + jr_) * 32 + 4 * f4_),                            \
                (__attribute__((address_space(3))) void*)(void*)(&Kt[nb][c_ * 4]),        \
                16, 0, 0);                                                                \
            __builtin_amdgcn_global_load_lds(                                             \
                (const __attribute__((address_space(1))) void*)(const void*)              \
                    (Vb + (size_t)(j0_ + jr_) * 32 + 4 * f4_),                            \
                (__attribute__((address_space(3))) void*)(void*)(&Vt[nb][c_ * 4]),        \
                16, 0, 0);                                                                \
        }                                                                                 \
        if (tid < 64) {                                                                   \
            float4 cc;                                                                    \
            cc.x = Cb[(size_t)(j0_ + tid) * 3 + 0];                                       \
            cc.y = Cb[(size_t)(j0_ + tid) * 3 + 1];                                       \
            cc.z = Cb[(size_t)(j0_ + tid) * 3 + 2];                                       \
            cc.w = 0.f;                                                                   \
            Ct[nb][tid] = cc;                                                             \
        }                                                                                 \
    }

    float m = -INFINITY, l = 0.f;
    float o[32];
    #pragma unroll
    for (int kd = 0; kd < 32; ++kd) o[kd] = 0.f;

    int cur = 0;
    STAGE(0, 0);
    asm volatile("s_waitcnt vmcnt(0)" ::: "memory");
    __syncthreads();

    const int jb = seg * 16;   // this wave's quarter within every tile

    #pragma unroll 1
    for (int t = 0; t < 32; ++t) {
        if (t < 31) STAGE(cur ^ 1, t + 1);   // prefetch next tile (no wait)

        const float* __restrict__ Kc = &Kt[cur][0];
        const float* __restrict__ Vc = &Vt[cur][0];

        float sv[16];
        float mt = -INFINITY;
        #pragma unroll
        for (int jj = 0; jj < 16; ++jj) {
            const int jl = jb + jj;
            const float4 c4 = Ct[cur][jl];            // broadcast ds_read
            const float dx = cix - c4.x;
            const float dy = ciy - c4.y;
            const float dz = ciz - c4.z;
            const float d2 = fmaf(dx, dx, fmaf(dy, dy, dz * dz));

            const float* __restrict__ kp = Kc + jl * 32;
            float p0 = 0.f, p1 = 0.f, p2 = 0.f, p3 = 0.f;
            #pragma unroll
            for (int u = 0; u < 8; ++u) {
                const float4 kv = *reinterpret_cast<const float4*>(kp + 4 * u);
                p0 = fmaf(qf[4 * u + 0], kv.x, p0);
                p1 = fmaf(qf[4 * u + 1], kv.y, p1);
                p2 = fmaf(qf[4 * u + 2], kv.z, p2);
                p3 = fmaf(qf[4 * u + 3], kv.w, p3);
            }
            const float qk = (p0 + p1) + (p2 + p3);
            const float rb = __expf(-d2 * inv2s2);
            const bool valid = (rb >= 0.01f) && (rb <= 0.99f);
            const float sc = valid ? qk * scale * (rb * rb) : -1e9f;
            sv[jj] = sc;
            mt = fmaxf(mt, sc);
        }

        const float mn = fmaxf(m, mt);
        const float em = __expf(m - mn);
        l *= em;
        #pragma unroll
        for (int kd = 0; kd < 32; ++kd) o[kd] *= em;

        #pragma unroll
        for (int jj = 0; jj < 16; ++jj) {
            const int jl = jb + jj;
            const float p = __expf(sv[jj] - mn);
            l += p;
            const float* __restrict__ vp = Vc + jl * 32;
            #pragma unroll
            for (int u = 0; u < 8; ++u) {
                const float4 vv = *reinterpret_cast<const float4*>(vp + 4 * u);
                o[4 * u + 0] = fmaf(p, vv.x, o[4 * u + 0]);
                o[4 * u + 1] = fmaf(p, vv.y, o[4 * u + 1]);
                o[4 * u + 2] = fmaf(p, vv.z, o[4 * u + 2]);
                o[4 * u + 3] = fmaf(p, vv.w, o[4 * u + 3]);
            }
        }
        m = mn;

        asm volatile("s_waitcnt vmcnt(0)" ::: "memory");  // next tile landed
        __syncthreads();                                   // all waves done with cur
        cur ^= 1;
    }
    #undef STAGE

    // ---- merge the 4 j-quarters via LDS (segs 1-3 publish, seg 0 merges) ----
    __shared__ float Lm[3][64];
    __shared__ float Ll[3][64];
    __shared__ float Lo[3][64][33];   // stride 33: conflict-free
    if (seg != 0) {
        Lm[seg - 1][r] = m;
        Ll[seg - 1][r] = l;
        #pragma unroll
        for (int kd = 0; kd < 32; ++kd) Lo[seg - 1][r][kd] = o[kd];
    }
    __syncthreads();
    if (seg == 0) {
        float mn = m;
        #pragma unroll
        for (int s = 0; s < 3; ++s) mn = fmaxf(mn, Lm[s][r]);
        const float e0 = __expf(m - mn);
        float lt = l * e0;
        float es[3];
        #pragma unroll
        for (int s = 0; s < 3; ++s) {
            es[s] = __expf(Lm[s][r] - mn);
            lt = fmaf(Ll[s][r], es[s], lt);
        }
        const float invl = 1.0f / lt;
        const size_t base = ((size_t)b * 2048 + i) * 512 + h;
        #pragma unroll
        for (int kd = 0; kd < 32; ++kd) {
            float acc = o[kd] * e0;
            #pragma unroll
            for (int s = 0; s < 3; ++s) acc = fmaf(Lo[s][r][kd], es[s], acc);
            pre[base + (size_t)kd * 16] = acc * invl;
        }
    }
}

// ---------------------------------------------------------------------------
// Kernel 3: out = pre @ w_out^T (unchanged).
// ---------------------------------------------------------------------------
__global__ __launch_bounds__(256) void out_proj_kernel(
    const float* __restrict__ pre, const float* __restrict__ w_out,
    float* __restrict__ out)
{
    const int m0 = blockIdx.x * 128;
    const int d0 = blockIdx.y * 64;

    __shared__ float XsT[32][132];
    __shared__ float Bs[32][68];

    const int tid = threadIdx.x;
    const int tx = tid & 15;
    const int ty = tid >> 4;

    float acc[8][4];
    #pragma unroll
    for (int i = 0; i < 8; ++i)
        #pragma unroll
        for (int j = 0; j < 4; ++j) acc[i][j] = 0.f;

    for (int k0 = 0; k0 < 512; k0 += 32) {
        __syncthreads();
        #pragma unroll
        for (int it = 0; it < 4; ++it) {
            int u = tid + 256 * it;
            int r = u >> 3, f = u & 7;
            float4 xv = *reinterpret_cast<const float4*>(&pre[(size_t)(m0 + r) * 512 + k0 + 4 * f]);
            XsT[4 * f + 0][r] = xv.x;
            XsT[4 * f + 1][r] = xv.y;
            XsT[4 * f + 2][r] = xv.z;
            XsT[4 * f + 3][r] = xv.w;
        }
        #pragma unroll
        for (int it = 0; it < 2; ++it) {
            int u = tid + 256 * it;
            int dd = u >> 3, cf = u & 7;
            float4 wv = *reinterpret_cast<const float4*>(&w_out[(size_t)(d0 + dd) * 512 + k0 + 4 * cf]);
            Bs[4 * cf + 0][dd] = wv.x;
            Bs[4 * cf + 1][dd] = wv.y;
            Bs[4 * cf + 2][dd] = wv.z;
            Bs[4 * cf + 3][dd] = wv.w;
        }
        __syncthreads();
        #pragma unroll
        for (int kk = 0; kk < 32; ++kk) {
            float4 a0 = *reinterpret_cast<const float4*>(&XsT[kk][8 * ty]);
            float4 a1 = *reinterpret_cast<const float4*>(&XsT[kk][8 * ty + 4]);
            float4 bv = *reinterpret_cast<const float4*>(&Bs[kk][4 * tx]);
            float ar[8] = {a0.x, a0.y, a0.z, a0.w, a1.x, a1.y, a1.z, a1.w};
            float br[4] = {bv.x, bv.y, bv.z, bv.w};
            #pragma unroll
            for (int i = 0; i < 8; ++i)
                #pragma unroll
                for (int j = 0; j < 4; ++j) acc[i][j] = fmaf(ar[i], br[j], acc[i][j]);
        }
    }

    #pragma unroll
    for (int i = 0; i < 8; ++i) {
        int m = m0 + 8 * ty + i;
        float4 ov;
        ov.x = acc[i][0];
        ov.y = acc[i][1];
        ov.z = acc[i][2];
        ov.w = acc[i][3];
        *reinterpret_cast<float4*>(&out[(size_t)m * 512 + d0 + 4 * tx]) = ov;
    }
}

// ---------------------------------------------------------------------------
extern "C" void kernel_launch(void* const* d_in, const int* in_sizes, int n_in,
                              void* d_out, int out_size, void* d_ws, size_t ws_size,
                              hipStream_t stream) {
    const float* q       = (const float*)d_in[0];
    const float* k       = (const float*)d_in[1];
    const float* v       = (const float*)d_in[2];
    const float* coords  = (const float*)d_in[3];
    const float* q_proj  = (const float*)d_in[4];
    const float* k_proj  = (const float*)d_in[5];
    const float* v_proj  = (const float*)d_in[6];
    const float* q_bias  = (const float*)d_in[7];
    const float* k_bias  = (const float*)d_in[8];
    const float* v_bias  = (const float*)d_in[9];
    const float* w_out   = (const float*)d_in[10];
    const float* spreads = (const float*)d_in[11];
    float* out = (float*)d_out;

    // workspace layout (floats): Q | K | V | pre   (each B*H*N*DK = 2M, pre = B*N*D = 2M)
    float* Qws = (float*)d_ws;
    float* Kws = Qws + (size_t)Bb * Hh * Nn * DKk;
    float* Vws = Kws + (size_t)Bb * Hh * Nn * DKk;
    float* pre = Vws + (size_t)Bb * Hh * Nn * DKk;

    {
        dim3 grid(4096 / 128, 512 / 64, 3);
        qkv_proj_kernel<<<grid, 256, 0, stream>>>(q, k, v, q_proj, k_proj, v_proj,
                                                  q_bias, k_bias, v_bias, Qws, Kws, Vws);
    }
    {
        dim3 grid(Nn / 64, Hh, Bb);
        attn_kernel<<<grid, 256, 0, stream>>>(Qws, Kws, Vws, coords, spreads, pre);
    }
    {
        dim3 grid(4096 / 128, 512 / 64);
        out_proj_kernel<<<grid, 256, 0, stream>>>(pre, w_out, out);
    }
}

// Round 12
// 568.058 us; speedup vs baseline: 4.2961x; 1.1796x over previous
//
#include <hip/hip_runtime.h>
#include <hip/hip_bf16.h>
#include <math.h>

#define Bb 2
#define Nn 2048
#define Dd 512
#define Hh 16
#define DKk 32

typedef float f32x2 __attribute__((ext_vector_type(2)));

static __device__ __forceinline__ f32x2 pkfma(f32x2 a, f32x2 b, f32x2 c) {
    return __builtin_elementwise_fma(a, b, c);
}

// ---------------------------------------------------------------------------
// Kernel 1: fused QKV projection. Inner microkernel packed to v_pk_fma_f32
// (2 f32 FMA per instruction): acc[8][4] as f32x2 acc2[8][2] over col pairs.
// ---------------------------------------------------------------------------
__global__ __launch_bounds__(256) void qkv_proj_kernel(
    const float* __restrict__ q, const float* __restrict__ k, const float* __restrict__ v,
    const float* __restrict__ q_proj, const float* __restrict__ k_proj, const float* __restrict__ v_proj,
    const float* __restrict__ q_bias, const float* __restrict__ k_bias, const float* __restrict__ v_bias,
    float* __restrict__ Qws, float* __restrict__ Kws, float* __restrict__ Vws)
{
    const int gz = blockIdx.z; // 0=q,1=k,2=v
    const float* __restrict__ X = (gz == 0) ? q : (gz == 1) ? k : v;
    const float* __restrict__ W = (gz == 0) ? q_proj : (gz == 1) ? k_proj : v_proj;
    const float* __restrict__ bias = (gz == 0) ? q_bias : (gz == 1) ? k_bias : v_bias;
    float* __restrict__ O = (gz == 0) ? Qws : (gz == 1) ? Kws : Vws;

    const int m0 = blockIdx.x * 128;
    const int c0 = blockIdx.y * 64;

    __shared__ float XsT[32][132];
    __shared__ float Ws[32][68];

    const int tid = threadIdx.x;
    const int tx = tid & 15;
    const int ty = tid >> 4;

    f32x2 acc2[8][2];
    #pragma unroll
    for (int i = 0; i < 8; ++i)
        #pragma unroll
        for (int j = 0; j < 2; ++j) acc2[i][j] = (f32x2)(0.f);

    for (int k0 = 0; k0 < 512; k0 += 32) {
        __syncthreads();
        #pragma unroll
        for (int it = 0; it < 4; ++it) {
            int u = tid + 256 * it;
            int r = u >> 3, f = u & 7;
            float4 xv = *reinterpret_cast<const float4*>(&X[(size_t)(m0 + r) * 512 + k0 + 4 * f]);
            XsT[4 * f + 0][r] = xv.x;
            XsT[4 * f + 1][r] = xv.y;
            XsT[4 * f + 2][r] = xv.z;
            XsT[4 * f + 3][r] = xv.w;
        }
        #pragma unroll
        for (int it = 0; it < 2; ++it) {
            int u = tid + 256 * it;
            int c4 = u & 15, kk = u >> 4;
            int c = c0 + 4 * c4;
            int h = c >> 5, dk = c & 31;
            float4 wv = *reinterpret_cast<const float4*>(&W[((size_t)h * 512 + k0 + kk) * 32 + dk]);
            *reinterpret_cast<float4*>(&Ws[kk][4 * c4]) = wv;
        }
        __syncthreads();
        #pragma unroll
        for (int kk = 0; kk < 32; ++kk) {
            float4 a0 = *reinterpret_cast<const float4*>(&XsT[kk][8 * ty]);
            float4 a1 = *reinterpret_cast<const float4*>(&XsT[kk][8 * ty + 4]);
            float4 bv = *reinterpret_cast<const float4*>(&Ws[kk][4 * tx]);
            const float ar[8] = {a0.x, a0.y, a0.z, a0.w, a1.x, a1.y, a1.z, a1.w};
            const f32x2 br0 = {bv.x, bv.y};
            const f32x2 br1 = {bv.z, bv.w};
            #pragma unroll
            for (int i = 0; i < 8; ++i) {
                const f32x2 ai = {ar[i], ar[i]};
                acc2[i][0] = pkfma(ai, br0, acc2[i][0]);
                acc2[i][1] = pkfma(ai, br1, acc2[i][1]);
            }
        }
    }

    const int c = c0 + 4 * tx;
    const int h = c >> 5, dk = c & 31;
    float4 bq = *reinterpret_cast<const float4*>(&bias[h * 32 + dk]);
    #pragma unroll
    for (int i = 0; i < 8; ++i) {
        int m = m0 + 8 * ty + i;
        int bb = m >> 11, n = m & 2047;
        float4 ov;
        ov.x = acc2[i][0].x + bq.x;
        ov.y = acc2[i][0].y + bq.y;
        ov.z = acc2[i][1].x + bq.z;
        ov.w = acc2[i][1].y + bq.w;
        *reinterpret_cast<float4*>(&O[(((size_t)bb * 16 + h) * 2048 + n) * 32 + dk]) = ov;
    }
}

// ---------------------------------------------------------------------------
// Kernel 2: RBF-gated flash attention, LDS-staged double-buffered K/V tiles
// (round-10: 488us, VALUBusy 66% -> VALU-issue-bound). This round: pack the
// QK dot (32 fma -> 16 pk-fma), PV accumulate (32 -> 16), and chunk rescale
// (32 -> 16) into v_pk_fma_f32 via f32x2 ext-vectors. LDS reads stay
// float4/b128 (f32x2 built from register pairs, NOT narrower ds_reads).
// ---------------------------------------------------------------------------
__global__ __launch_bounds__(256) void attn_kernel(
    const float* __restrict__ Qws, const float* __restrict__ Kws, const float* __restrict__ Vws,
    const float* __restrict__ coords, const float* __restrict__ spreads,
    float* __restrict__ pre)
{
    const int b = blockIdx.z, h = blockIdx.y;
    const int tid = threadIdx.x;
    const int r = tid & 63;        // query row within block (lane)
    const int seg = tid >> 6;      // wave id = j-quarter within each tile
    const int i = blockIdx.x * 64 + r;
    const int bh = b * 16 + h;

    const float sig = spreads[h];
    const float inv2s2 = 1.0f / (2.0f * sig * sig);
    const float scale = 0.17677669529663687f;   // 1/sqrt(32)

    const float* __restrict__ Cb = coords + (size_t)b * 2048 * 3;
    const float* __restrict__ Kb = Kws + (size_t)bh * 2048 * 32;
    const float* __restrict__ Vb = Vws + (size_t)bh * 2048 * 32;

    const float cix = Cb[(size_t)i * 3 + 0];
    const float ciy = Cb[(size_t)i * 3 + 1];
    const float ciz = Cb[(size_t)i * 3 + 2];

    f32x2 qf2[16];
    #pragma unroll
    for (int u = 0; u < 8; ++u) {
        float4 t = *reinterpret_cast<const float4*>(&Qws[((size_t)bh * 2048 + i) * 32 + 4 * u]);
        qf2[2 * u + 0] = {t.x, t.y};
        qf2[2 * u + 1] = {t.z, t.w};
    }

    // double-buffered tiles: K,V 64x32 f32 each; coords 64x float4
    __shared__ float Kt[2][64 * 32];   // 16 KB
    __shared__ float Vt[2][64 * 32];   // 16 KB
    __shared__ float4 Ct[2][64];       // 2 KB

    #define STAGE(nb, t)                                                                  \
    {                                                                                     \
        const int j0_ = (t) * 64;                                                         \
        _Pragma("unroll")                                                                 \
        for (int it_ = 0; it_ < 2; ++it_) {                                               \
            const int c_ = tid + it_ * 256;                                               \
            const int jr_ = c_ >> 3, f4_ = c_ & 7;                                        \
            __builtin_amdgcn_global_load_lds(                                             \
                (const __attribute__((address_space(1))) void*)(const void*)              \
                    (Kb + (size_t)(j0_ + jr_) * 32 + 4 * f4_),                            \
                (__attribute__((address_space(3))) void*)(void*)(&Kt[nb][c_ * 4]),        \
                16, 0, 0);                                                                \
            __builtin_amdgcn_global_load_lds(                                             \
                (const __attribute__((address_space(1))) void*)(const void*)              \
                    (Vb + (size_t)(j0_ + jr_) * 32 + 4 * f4_),                            \
                (__attribute__((address_space(3))) void*)(void*)(&Vt[nb][c_ * 4]),        \
                16, 0, 0);                                                                \
        }                                                                                 \
        if (tid < 64) {                                                                   \
            float4 cc;                                                                    \
            cc.x = Cb[(size_t)(j0_ + tid) * 3 + 0];                                       \
            cc.y = Cb[(size_t)(j0_ + tid) * 3 + 1];                                       \
            cc.z = Cb[(size_t)(j0_ + tid) * 3 + 2];                                       \
            cc.w = 0.f;                                                                   \
            Ct[nb][tid] = cc;                                                             \
        }                                                                                 \
    }

    float m = -INFINITY, l = 0.f;
    f32x2 o2[16];
    #pragma unroll
    for (int u = 0; u < 16; ++u) o2[u] = (f32x2)(0.f);

    int cur = 0;
    STAGE(0, 0);
    asm volatile("s_waitcnt vmcnt(0)" ::: "memory");
    __syncthreads();

    const int jb = seg * 16;   // this wave's quarter within every tile

    #pragma unroll 1
    for (int t = 0; t < 32; ++t) {
        if (t < 31) STAGE(cur ^ 1, t + 1);   // prefetch next tile (no wait)

        const float* __restrict__ Kc = &Kt[cur][0];
        const float* __restrict__ Vc = &Vt[cur][0];

        float sv[16];
        float mt = -INFINITY;
        #pragma unroll
        for (int jj = 0; jj < 16; ++jj) {
            const int jl = jb + jj;
            const float4 c4 = Ct[cur][jl];            // broadcast ds_read
            const float dx = cix - c4.x;
            const float dy = ciy - c4.y;
            const float dz = ciz - c4.z;
            const float d2 = fmaf(dx, dx, fmaf(dy, dy, dz * dz));

            const float* __restrict__ kp = Kc + jl * 32;
            f32x2 pa = (f32x2)(0.f), pb = (f32x2)(0.f);
            f32x2 pc = (f32x2)(0.f), pd = (f32x2)(0.f);
            #pragma unroll
            for (int u = 0; u < 4; ++u) {
                const float4 k0 = *reinterpret_cast<const float4*>(kp + 8 * u);
                const float4 k1 = *reinterpret_cast<const float4*>(kp + 8 * u + 4);
                pa = pkfma(qf2[4 * u + 0], (f32x2){k0.x, k0.y}, pa);
                pb = pkfma(qf2[4 * u + 1], (f32x2){k0.z, k0.w}, pb);
                pc = pkfma(qf2[4 * u + 2], (f32x2){k1.x, k1.y}, pc);
                pd = pkfma(qf2[4 * u + 3], (f32x2){k1.z, k1.w}, pd);
            }
            const f32x2 ps = (pa + pb) + (pc + pd);
            const float qk = ps.x + ps.y;
            const float rb = __expf(-d2 * inv2s2);
            const bool valid = (rb >= 0.01f) && (rb <= 0.99f);
            const float sc = valid ? qk * scale * (rb * rb) : -1e9f;
            sv[jj] = sc;
            mt = fmaxf(mt, sc);
        }

        const float mn = fmaxf(m, mt);
        const float em = __expf(m - mn);
        l *= em;
        const f32x2 em2 = {em, em};
        #pragma unroll
        for (int u = 0; u < 16; ++u) o2[u] *= em2;

        #pragma unroll
        for (int jj = 0; jj < 16; ++jj) {
            const int jl = jb + jj;
            const float p = __expf(sv[jj] - mn);
            l += p;
            const f32x2 pp = {p, p};
            const float* __restrict__ vp = Vc + jl * 32;
            #pragma unroll
            for (int u = 0; u < 4; ++u) {
                const float4 v0 = *reinterpret_cast<const float4*>(vp + 8 * u);
                const float4 v1 = *reinterpret_cast<const float4*>(vp + 8 * u + 4);
                o2[4 * u + 0] = pkfma(pp, (f32x2){v0.x, v0.y}, o2[4 * u + 0]);
                o2[4 * u + 1] = pkfma(pp, (f32x2){v0.z, v0.w}, o2[4 * u + 1]);
                o2[4 * u + 2] = pkfma(pp, (f32x2){v1.x, v1.y}, o2[4 * u + 2]);
                o2[4 * u + 3] = pkfma(pp, (f32x2){v1.z, v1.w}, o2[4 * u + 3]);
            }
        }
        m = mn;

        asm volatile("s_waitcnt vmcnt(0)" ::: "memory");  // next tile landed
        __syncthreads();                                   // all waves done with cur
        cur ^= 1;
    }
    #undef STAGE

    // ---- merge the 4 j-quarters via LDS (segs 1-3 publish, seg 0 merges) ----
    __shared__ float Lm[3][64];
    __shared__ float Ll[3][64];
    __shared__ float Lo[3][64][33];   // stride 33: conflict-free
    if (seg != 0) {
        Lm[seg - 1][r] = m;
        Ll[seg - 1][r] = l;
        #pragma unroll
        for (int u = 0; u < 16; ++u) {
            Lo[seg - 1][r][2 * u + 0] = o2[u].x;
            Lo[seg - 1][r][2 * u + 1] = o2[u].y;
        }
    }
    __syncthreads();
    if (seg == 0) {
        float mn = m;
        #pragma unroll
        for (int s = 0; s < 3; ++s) mn = fmaxf(mn, Lm[s][r]);
        const float e0 = __expf(m - mn);
        float lt = l * e0;
        float es[3];
        #pragma unroll
        for (int s = 0; s < 3; ++s) {
            es[s] = __expf(Lm[s][r] - mn);
            lt = fmaf(Ll[s][r], es[s], lt);
        }
        const float invl = 1.0f / lt;
        const size_t base = ((size_t)b * 2048 + i) * 512 + h;
        #pragma unroll
        for (int u = 0; u < 16; ++u) {
            f32x2 acc = o2[u] * (f32x2){e0, e0};
            #pragma unroll
            for (int s = 0; s < 3; ++s) {
                const f32x2 lo = {Lo[s][r][2 * u + 0], Lo[s][r][2 * u + 1]};
                acc = pkfma(lo, (f32x2){es[s], es[s]}, acc);
            }
            pre[base + (size_t)(2 * u + 0) * 16] = acc.x * invl;
            pre[base + (size_t)(2 * u + 1) * 16] = acc.y * invl;
        }
    }
}

// ---------------------------------------------------------------------------
// Kernel 3: out = pre @ w_out^T. Packed f32x2 microkernel like kernel 1.
// ---------------------------------------------------------------------------
__global__ __launch_bounds__(256) void out_proj_kernel(
    const float* __restrict__ pre, const float* __restrict__ w_out,
    float* __restrict__ out)
{
    const int m0 = blockIdx.x * 128;
    const int d0 = blockIdx.y * 64;

    __shared__ float XsT[32][132];
    __shared__ float Bs[32][68];

    const int tid = threadIdx.x;
    const int tx = tid & 15;
    const int ty = tid >> 4;

    f32x2 acc2[8][2];
    #pragma unroll
    for (int i = 0; i < 8; ++i)
        #pragma unroll
        for (int j = 0; j < 2; ++j) acc2[i][j] = (f32x2)(0.f);

    for (int k0 = 0; k0 < 512; k0 += 32) {
        __syncthreads();
        #pragma unroll
        for (int it = 0; it < 4; ++it) {
            int u = tid + 256 * it;
            int r = u >> 3, f = u & 7;
            float4 xv = *reinterpret_cast<const float4*>(&pre[(size_t)(m0 + r) * 512 + k0 + 4 * f]);
            XsT[4 * f + 0][r] = xv.x;
            XsT[4 * f + 1][r] = xv.y;
            XsT[4 * f + 2][r] = xv.z;
            XsT[4 * f + 3][r] = xv.w;
        }
        #pragma unroll
        for (int it = 0; it < 2; ++it) {
            int u = tid + 256 * it;
            int dd = u >> 3, cf = u & 7;
            float4 wv = *reinterpret_cast<const float4*>(&w_out[(size_t)(d0 + dd) * 512 + k0 + 4 * cf]);
            Bs[4 * cf + 0][dd] = wv.x;
            Bs[4 * cf + 1][dd] = wv.y;
            Bs[4 * cf + 2][dd] = wv.z;
            Bs[4 * cf + 3][dd] = wv.w;
        }
        __syncthreads();
        #pragma unroll
        for (int kk = 0; kk < 32; ++kk) {
            float4 a0 = *reinterpret_cast<const float4*>(&XsT[kk][8 * ty]);
            float4 a1 = *reinterpret_cast<const float4*>(&XsT[kk][8 * ty + 4]);
            float4 bv = *reinterpret_cast<const float4*>(&Bs[kk][4 * tx]);
            const float ar[8] = {a0.x, a0.y, a0.z, a0.w, a1.x, a1.y, a1.z, a1.w};
            const f32x2 br0 = {bv.x, bv.y};
            const f32x2 br1 = {bv.z, bv.w};
            #pragma unroll
            for (int i = 0; i < 8; ++i) {
                const f32x2 ai = {ar[i], ar[i]};
                acc2[i][0] = pkfma(ai, br0, acc2[i][0]);
                acc2[i][1] = pkfma(ai, br1, acc2[i][1]);
            }
        }
    }

    #pragma unroll
    for (int i = 0; i < 8; ++i) {
        int m = m0 + 8 * ty + i;
        float4 ov;
        ov.x = acc2[i][0].x;
        ov.y = acc2[i][0].y;
        ov.z = acc2[i][1].x;
        ov.w = acc2[i][1].y;
        *reinterpret_cast<float4*>(&out[(size_t)m * 512 + d0 + 4 * tx]) = ov;
    }
}

// ---------------------------------------------------------------------------
extern "C" void kernel_launch(void* const* d_in, const int* in_sizes, int n_in,
                              void* d_out, int out_size, void* d_ws, size_t ws_size,
                              hipStream_t stream) {
    const float* q       = (const float*)d_in[0];
    const float* k       = (const float*)d_in[1];
    const float* v       = (const float*)d_in[2];
    const float* coords  = (const float*)d_in[3];
    const float* q_proj  = (const float*)d_in[4];
    const float* k_proj  = (const float*)d_in[5];
    const float* v_proj  = (const float*)d_in[6];
    const float* q_bias  = (const float*)d_in[7];
    const float* k_bias  = (const float*)d_in[8];
    const float* v_bias  = (const float*)d_in[9];
    const float* w_out   = (const float*)d_in[10];
    const float* spreads = (const float*)d_in[11];
    float* out = (float*)d_out;

    // workspace layout (floats): Q | K | V | pre   (each B*H*N*DK = 2M, pre = B*N*D = 2M)
    float* Qws = (float*)d_ws;
    float* Kws = Qws + (size_t)Bb * Hh * Nn * DKk;
    float* Vws = Kws + (size_t)Bb * Hh * Nn * DKk;
    float* pre = Vws + (size_t)Bb * Hh * Nn * DKk;

    {
        dim3 grid(4096 / 128, 512 / 64, 3);
        qkv_proj_kernel<<<grid, 256, 0, stream>>>(q, k, v, q_proj, k_proj, v_proj,
                                                  q_bias, k_bias, v_bias, Qws, Kws, Vws);
    }
    {
        dim3 grid(Nn / 64, Hh, Bb);
        attn_kernel<<<grid, 256, 0, stream>>>(Qws, Kws, Vws, coords, spreads, pre);
    }
    {
        dim3 grid(4096 / 128, 512 / 64);
        out_proj_kernel<<<grid, 256, 0, stream>>>(pre, w_out, out);
    }
}